// Round 5
// baseline (391.270 us; speedup 1.0000x reference)
//
#include <hip/hip_runtime.h>

// SDPAttention (bug-faithful: output = masked_scores @ v, NOT softmax @ v)
// B=4 H=16 S=1024 DK=64, fp32 in/out.
// R5: non-temporal hints. The 268MB attn_weight write stream was thrashing
// the 4MB per-XCD L2s, evicting the K/V fragment working set and forcing all
// re-reads to L3/HBM (attn_main ~3.4 TB/s effective). nt stores (evict-first)
// for attn+output; nt loads for single-use Q and pack-kernel K/V reads.
// d_ws: [0,8MB) KbT[bh][kt][lane][16]; [8MB,16MB) VtP[bh][dt][ks][lane][8]

typedef __attribute__((ext_vector_type(4))) float floatx4;
typedef __attribute__((ext_vector_type(8))) short shortx8;
typedef __attribute__((ext_vector_type(8))) unsigned short ushortx8;
typedef __attribute__((ext_vector_type(4))) int intx4;

#define S_ 1024
#define D_ 64
#define NELEM_ 4194304      // B*H*S*DK
#define ATTN_OFF 4194304    // output elements before attn_weight
#define SCN 1040            // LDS score row stride (ushorts); 2080B rows, 16B aligned

__device__ __forceinline__ unsigned short f32_to_bf16(float f) {
    union { float f; unsigned u; } a; a.f = f;
    unsigned u = a.u;
    u += 0x7fffu + ((u >> 16) & 1u);   // round-to-nearest-even
    return (unsigned short)(u >> 16);
}

__device__ __forceinline__ float bf16_to_f32(unsigned short h) {
    union { unsigned u; float f; } a; a.u = ((unsigned)h) << 16;
    return a.f;
}

__device__ __forceinline__ ushortx8 pack8u(floatx4 a, floatx4 b) {
    ushortx8 r;
    r[0] = f32_to_bf16(a[0]); r[1] = f32_to_bf16(a[1]);
    r[2] = f32_to_bf16(a[2]); r[3] = f32_to_bf16(a[3]);
    r[4] = f32_to_bf16(b[0]); r[5] = f32_to_bf16(b[1]);
    r[6] = f32_to_bf16(b[2]); r[7] = f32_to_bf16(b[3]);
    return r;
}

// ---- merged pre-kernel: blocks [0,1024) pack K, [1024,2048) pack V ----
__global__ __launch_bounds__(256) void pack_kv(const float* __restrict__ k,
                                               const float* __restrict__ v,
                                               unsigned short* __restrict__ kbt,
                                               unsigned short* __restrict__ vtp) {
    __shared__ float tile[64][65];
    if (blockIdx.x < 1024) {
        // K fp32 [bh][s][d] -> KbT fragment-major bf16
        int g = blockIdx.x * 256 + threadIdx.x;   // 262144 total
        int lane = g & 63;
        int kt   = (g >> 6) & 63;
        int bh   = g >> 12;
        int quad = lane >> 4;
        int l15  = lane & 15;
        const float* src = k + ((size_t)(bh * S_ + kt * 16 + l15)) * D_ + quad * 8;
        floatx4 f0 = __builtin_nontemporal_load((const floatx4*)(src));
        floatx4 f1 = __builtin_nontemporal_load((const floatx4*)(src + 4));
        floatx4 f2 = __builtin_nontemporal_load((const floatx4*)(src + 32));
        floatx4 f3 = __builtin_nontemporal_load((const floatx4*)(src + 36));
        unsigned short* dst = kbt + (size_t)g * 16;
        *(ushortx8*)(dst)     = pack8u(f0, f1);
        *(ushortx8*)(dst + 8) = pack8u(f2, f3);
    } else {
        // V fp32 [bh][s][d] -> VtP fragment-major bf16 via LDS transpose
        int blk = blockIdx.x - 1024;
        int bh = blk >> 4;
        int s0 = (blk & 15) << 6;
        int tid = threadIdx.x;
        int r  = tid >> 2;
        int c0 = (tid & 3) << 4;
        const float* src = v + ((size_t)(bh * S_ + s0 + r)) * D_ + c0;
        #pragma unroll
        for (int j = 0; j < 4; ++j) {
            floatx4 f = __builtin_nontemporal_load((const floatx4*)(src + j * 4));
            tile[r][c0 + j*4 + 0] = f[0];
            tile[r][c0 + j*4 + 1] = f[1];
            tile[r][c0 + j*4 + 2] = f[2];
            tile[r][c0 + j*4 + 3] = f[3];
        }
        __syncthreads();
        int d  = tid >> 2;          // 0..63
        int so = (tid & 3) << 4;    // 0,16,32,48
        int dt  = d >> 4;
        int l15 = d & 15;
        ushortx8 h0, h1;
        #pragma unroll
        for (int j = 0; j < 8; ++j) h0[j] = f32_to_bf16(tile[so + j][d]);
        #pragma unroll
        for (int j = 0; j < 8; ++j) h1[j] = f32_to_bf16(tile[so + 8 + j][d]);
        int sA = s0 + so;
        int ksA = sA >> 5, qA = (sA & 31) >> 3;
        int sB = sA + 8;
        int ksB = sB >> 5, qB = (sB & 31) >> 3;
        size_t baseA = ((((size_t)bh * 4 + dt) * 32 + ksA) * 64 + qA * 16 + l15) * 8;
        size_t baseB = ((((size_t)bh * 4 + dt) * 32 + ksB) * 64 + qB * 16 + l15) * 8;
        *(ushortx8*)(vtp + baseA) = h0;
        *(ushortx8*)(vtp + baseB) = h1;
    }
}

// ---- main: per-block = (bh, 64-row q tile); 16 waves = 4 rg x 4 cg ----
__global__ __launch_bounds__(1024, 4) void attn_main(
    const float* __restrict__ q,
    const int* __restrict__ mask,
    const unsigned short* __restrict__ KbT,
    const unsigned short* __restrict__ VtP,
    float* __restrict__ out)
{
    __shared__ unsigned short sc[64 * SCN];   // 133,120 B masked scaled scores (bf16)
    __shared__ int msk[1024];

    int blk = blockIdx.x;             // 1024 blocks
    int bh  = blk >> 4;
    int q0  = (blk & 15) << 6;
    int b   = bh >> 4;
    int tid = threadIdx.x;

    msk[tid] = mask[(b << 10) + tid];

    int w    = tid >> 6;              // 0..15
    int lane = tid & 63;
    int l15  = lane & 15;
    int quad = lane >> 4;
    int rg   = w & 3;                 // row-group: q rows [rg*16, rg*16+16)
    int cg   = w >> 2;                // col-group: kt in [cg*16, cg*16+16) / d-tile cg

    // Q fragments (A: m=lane&15 (q row within tile), k=quad*8+j (d)); single-use -> nt
    shortx8 qf0, qf1;
    {
        const float* qb = q + ((size_t)(bh * S_ + q0 + rg * 16 + l15)) * D_ + quad * 8;
        floatx4 a0 = __builtin_nontemporal_load((const floatx4*)(qb));
        floatx4 a1 = __builtin_nontemporal_load((const floatx4*)(qb + 4));
        floatx4 b0 = __builtin_nontemporal_load((const floatx4*)(qb + 32));
        floatx4 b1 = __builtin_nontemporal_load((const floatx4*)(qb + 36));
        ushortx8 u0 = pack8u(a0, a1);
        ushortx8 u1 = pack8u(b0, b1);
        qf0 = (shortx8)u0;
        qf1 = (shortx8)u1;
    }

    __syncthreads();

    // ---- Phase 1: Sc = scale*QK^T, masked, -> LDS bf16 ----
    {
        const unsigned short* kb = KbT + ((size_t)bh * 64 * 64 + lane) * 16;
        #pragma unroll 4
        for (int t = 0; t < 16; ++t) {
            int kt = (cg << 4) + t;
            const unsigned short* p = kb + (size_t)kt * (64 * 16);
            shortx8 kf0 = *(const shortx8*)(p);       // cached: K/V stay L2-resident
            shortx8 kf1 = *(const shortx8*)(p + 8);
            floatx4 acc = {0.f, 0.f, 0.f, 0.f};
            acc = __builtin_amdgcn_mfma_f32_16x16x32_bf16(qf0, kf0, acc, 0, 0, 0);
            acc = __builtin_amdgcn_mfma_f32_16x16x32_bf16(qf1, kf1, acc, 0, 0, 0);
            int n0 = kt << 4;
            int mv = msk[n0 + l15];
            int col = n0 + l15;
            #pragma unroll
            for (int r = 0; r < 4; ++r) {
                // C/D: row(q within 16-tile) = quad*4+r, col(key) = lane&15
                unsigned short h = mv ? f32_to_bf16(acc[r] * 0.125f)
                                      : (unsigned short)0xC61C;  // bf16(-10000) = -9984
                sc[(rg * 16 + quad * 4 + r) * SCN + col] = h;
            }
        }
    }
    __syncthreads();

    // ---- Phase 2: row softmax -> attn_weight; Phase 3: O = Sc @ V ----
    // Independent (reference bug: O uses raw masked scores). Stagger by wave
    // parity so HBM-write burst (P2) overlaps MFMA/read burst (P3).
    auto phase2 = [&]() {
        float* attnb = out + ATTN_OFF + ((size_t)(bh * S_ + q0)) * S_;
        for (int rr = 0; rr < 4; ++rr) {
            int row = (w << 2) + rr;                 // w=0..15 -> rows 0..63
            const unsigned short* srow = sc + row * SCN;
            float vv[16];
            #pragma unroll
            for (int c = 0; c < 2; ++c) {
                ushortx8 h = *(const ushortx8*)(srow + (c << 9) + lane * 8);
                #pragma unroll
                for (int j = 0; j < 8; ++j) vv[c * 8 + j] = bf16_to_f32(h[j]);
            }
            float m = vv[0];
            #pragma unroll
            for (int j = 1; j < 16; ++j) m = fmaxf(m, vv[j]);
            #pragma unroll
            for (int off = 32; off; off >>= 1) m = fmaxf(m, __shfl_xor(m, off));
            float s = 0.f;
            #pragma unroll
            for (int j = 0; j < 16; ++j) { vv[j] = __expf(vv[j] - m); s += vv[j]; }
            #pragma unroll
            for (int off = 32; off; off >>= 1) s += __shfl_xor(s, off);
            float inv = 1.0f / s;
            float* arow = attnb + (size_t)row * S_ + lane * 8;
            #pragma unroll
            for (int c = 0; c < 2; ++c) {
                floatx4 o0 = { vv[c*8+0]*inv, vv[c*8+1]*inv, vv[c*8+2]*inv, vv[c*8+3]*inv };
                floatx4 o1 = { vv[c*8+4]*inv, vv[c*8+5]*inv, vv[c*8+6]*inv, vv[c*8+7]*inv };
                __builtin_nontemporal_store(o0, (floatx4*)(arow + (c << 9)));
                __builtin_nontemporal_store(o1, (floatx4*)(arow + (c << 9) + 4));
            }
        }
    };
    auto phase3 = [&]() {
        // wave (rg,cg): O tile rows [rg*16..), d cols [cg*16..)
        const unsigned short* vb = VtP + (((size_t)bh * 4 + cg) * 32) * (64 * 8) + lane * 8;
        const unsigned short* sr = sc + (rg * 16 + l15) * SCN + quad * 8;
        floatx4 oacc = {0.f, 0.f, 0.f, 0.f};
        #pragma unroll 4
        for (int ks = 0; ks < 32; ++ks) {
            shortx8 af = *(const shortx8*)(sr + (ks << 5));        // LDS A-frag
            shortx8 bf = *(const shortx8*)(vb + (ks << 9));        // cached 16B/lane
            oacc = __builtin_amdgcn_mfma_f32_16x16x32_bf16(af, bf, oacc, 0, 0, 0);
        }
        float* ob = out + ((size_t)(bh * S_ + q0 + rg * 16 + (quad << 2))) * D_
                        + (cg << 4) + l15;
        #pragma unroll
        for (int r = 0; r < 4; ++r)
            __builtin_nontemporal_store(oacc[r], ob + (size_t)r * D_);
    };
    if (w & 1) { phase3(); phase2(); }
    else       { phase2(); phase3(); }
}

extern "C" void kernel_launch(void* const* d_in, const int* in_sizes, int n_in,
                              void* d_out, int out_size, void* d_ws, size_t ws_size,
                              hipStream_t stream) {
    const float* q   = (const float*)d_in[0];
    const float* k   = (const float*)d_in[1];
    const float* v   = (const float*)d_in[2];
    const int* mask  = (const int*)d_in[3];
    float* out = (float*)d_out;
    unsigned short* KbT = (unsigned short*)d_ws;       // 8 MB
    unsigned short* VtP = KbT + NELEM_;                // 8 MB
    pack_kv<<<2048, 256, 0, stream>>>(k, v, KbT, VtP);
    attn_main<<<1024, 1024, 0, stream>>>(q, mask, KbT, VtP, out);
}